// Round 3
// baseline (1325.879 us; speedup 1.0000x reference)
//
#include <hip/hip_runtime.h>
#include <cstdint>

#define VOCAB 100000
#define EMB 300
#define NE 301         // 300 emb dims + 1 bias row (evoke_b)
#define KP 128         // padded h (bf16 elements per tv row)
#define EKSTRIDE 28672 // bytes per e slab = 7 tiles * 4 ks * 64 lanes * 16B
#define NP 128         // G row stride (floats)
#define BM 64
#define BTOT 16384

typedef __attribute__((ext_vector_type(8))) short short8;
typedef __attribute__((ext_vector_type(4))) float f32x4;

__device__ __forceinline__ unsigned short f2bf(float f) {
    uint32_t u = __float_as_uint(f);
    uint32_t r = (u + 0x7fffu + ((u >> 16) & 1u)) >> 16;   // RNE
    return (unsigned short)r;
}

// ---------------------------------------------------------------------------
// Prep 1: pack evoke_k (+ evoke_b as e=300) into bf16 in MFMA B-fragment order:
// slab[e] layout = [tile t(7)][ks(4)][lane(64)] x 16B, where the fragment for
// (t,ks,lane) covers p = t*16 + (lane&15), h = ks*32 + (lane>>4)*8 .. +7.
// Hot-loop loads become wave-contiguous 1KB reads.
// ---------------------------------------------------------------------------
__global__ __launch_bounds__(256) void k_ekprep(const float* __restrict__ evoke_k,
                                                const float* __restrict__ evoke_b,
                                                unsigned short* __restrict__ ekp) {
    int e = blockIdx.x;            // 0..300
    int tid = threadIdx.x;
    const float* src = (e < EMB) ? (evoke_k + (size_t)e * 10000) : evoke_b;
    uint32_t* dst = (uint32_t*)ekp + (size_t)e * (EKSTRIDE / 4);
#pragma unroll
    for (int i = 0; i < 7; ++i) {
        int g    = i * 256 + tid;      // 0..1791 fragment index
        int t    = g >> 8;             // tile 0..6
        int r    = g & 255;
        int ks   = r >> 6;
        int lane = r & 63;
        int p    = t * 16 + (lane & 15);
        int h0   = ks * 32 + (lane >> 4) * 8;
        float v[8];
        if (p < 100 && h0 + 7 < 100) {
            float4 a = *(const float4*)(src + p * 100 + h0);
            float4 b = *(const float4*)(src + p * 100 + h0 + 4);
            v[0] = a.x; v[1] = a.y; v[2] = a.z; v[3] = a.w;
            v[4] = b.x; v[5] = b.y; v[6] = b.z; v[7] = b.w;
        } else {
#pragma unroll
            for (int j = 0; j < 8; ++j) {
                int h = h0 + j;
                v[j] = (p < 100 && h < 100) ? src[p * 100 + h] : 0.f;
            }
        }
        uint32_t od[4];
#pragma unroll
        for (int k = 0; k < 4; ++k) {
            od[k] = (uint32_t)f2bf(v[2 * k]) | ((uint32_t)f2bf(v[2 * k + 1]) << 16);
        }
        *(uint4*)(dst + g * 4) = make_uint4(od[0], od[1], od[2], od[3]);
    }
}

// ---------------------------------------------------------------------------
// Prep 2: time MLP -> tv, stored bf16 [B][128] (h padded with zeros)
// ---------------------------------------------------------------------------
__global__ __launch_bounds__(256) void k_tv(const float* __restrict__ times,
                                            const float* __restrict__ h1_k,
                                            const float* __restrict__ h1_b,
                                            const float* __restrict__ h2_k,
                                            const float* __restrict__ h2_b,
                                            unsigned short* __restrict__ tvp) {
    __shared__ float h1s[16][100];
    int b0 = blockIdx.x * 16;
    for (int idx = threadIdx.x; idx < 1600; idx += 256) {
        int bb = idx / 100, i = idx - bb * 100;
        h1s[bb][i] = tanhf(times[b0 + bb] * h1_k[i] + h1_b[i]);
    }
    __syncthreads();
    for (int idx = threadIdx.x; idx < 1600; idx += 256) {
        int bb = idx / 100, j = idx - bb * 100;
        float acc = h2_b[j];
        for (int i = 0; i < 100; ++i) acc += h1s[bb][i] * h2_k[i * 100 + j];
        tvp[(size_t)(b0 + bb) * KP + j] = f2bf(tanhf(acc));
    }
    for (int idx = threadIdx.x; idx < 16 * 28; idx += 256) {
        int bb = idx / 28, j = 100 + (idx - bb * 28);
        tvp[(size_t)(b0 + bb) * KP + j] = 0;
    }
}

// ---------------------------------------------------------------------------
// Prep 3 (coalesced): 16 blocks compute 32x32 tiles of G = L L^T via LDS-staged
// rows (stride 301 to avoid bank conflicts). qt==0 blocks also compute vvec;
// block 0 computes c0 and zeroes out.
// ---------------------------------------------------------------------------
__global__ __launch_bounds__(256) void k_gprep(const float* __restrict__ last_k,
                                               const float* __restrict__ last_b,
                                               float* __restrict__ G,
                                               float* __restrict__ vvec,
                                               float* __restrict__ c0,
                                               float* __restrict__ out) {
    extern __shared__ float lds[];
    float* Lp = lds;               // [32][301]
    float* Lq = lds + 32 * 301;    // [32][301]
    int bx = blockIdx.x;           // 0..15
    int pt = bx >> 2, qt = bx & 3;
    int tid = threadIdx.x;
    int i   = tid >> 3;            // 0..31 (staging row)
    int sub = tid & 7;
    {
        int pr = pt * 32 + i;
        int qr = qt * 32 + i;
        for (int k4 = sub; k4 < 75; k4 += 8) {
            int d = k4 * 4;
            float4 vp = (pr < 100) ? *(const float4*)(last_k + pr * 300 + d)
                                   : make_float4(0.f, 0.f, 0.f, 0.f);
            float4 vq = (qr < 100) ? *(const float4*)(last_k + qr * 300 + d)
                                   : make_float4(0.f, 0.f, 0.f, 0.f);
            Lp[i * 301 + d + 0] = vp.x; Lp[i * 301 + d + 1] = vp.y;
            Lp[i * 301 + d + 2] = vp.z; Lp[i * 301 + d + 3] = vp.w;
            Lq[i * 301 + d + 0] = vq.x; Lq[i * 301 + d + 1] = vq.y;
            Lq[i * 301 + d + 2] = vq.z; Lq[i * 301 + d + 3] = vq.w;
        }
    }
    __syncthreads();
    int j  = tid & 31;
    int i0 = tid >> 5;             // 0..7
    float acc[4] = {0.f, 0.f, 0.f, 0.f};
    for (int d = 0; d < 300; ++d) {
        float qv = Lq[j * 301 + d];
#pragma unroll
        for (int r = 0; r < 4; ++r) acc[r] += Lp[(i0 + 8 * r) * 301 + d] * qv;
    }
#pragma unroll
    for (int r = 0; r < 4; ++r) {
        G[(pt * 32 + i0 + 8 * r) * NP + qt * 32 + j] = acc[r];
    }
    if (qt == 0) {   // vvec for this block's 32 p-rows (zero rows -> 0)
        float pa = 0.f;
        for (int d = sub; d < 300; d += 8) pa += Lp[i * 301 + d] * last_b[d];
        pa += __shfl_xor(pa, 1);
        pa += __shfl_xor(pa, 2);
        pa += __shfl_xor(pa, 4);
        if (sub == 0) vvec[pt * 32 + i] = pa;
    }
    if (bx == 0 && tid < 64) {
        float s = 0.f;
        for (int d = tid; d < 300; d += 64) s += last_b[d] * last_b[d];
#pragma unroll
        for (int off = 1; off < 64; off <<= 1) s += __shfl_xor(s, off);
        if (tid == 0) { *c0 = s; *out = 0.f; }
    }
}

// ---------------------------------------------------------------------------
// Main: 512 threads (8 waves). Wave group 0 (waves 0-3) handles even e,
// group 1 (waves 4-7) odd e; partials combined in LDS. Within a group, each
// wave owns 2 p-tiles; EK fragments loaded global->VGPR (wave-contiguous 1KB),
// 2-deep pipelined; NO per-iteration barriers (2 restage barriers total).
// ---------------------------------------------------------------------------
__global__ __launch_bounds__(512, 2) void k_main(
    const int* __restrict__ targets, const int* __restrict__ contexts,
    const float* __restrict__ labels,
    const float* __restrict__ targetemb, const float* __restrict__ contextemb,
    const unsigned short* __restrict__ ekp, const unsigned short* __restrict__ tvp,
    const float* __restrict__ G, const float* __restrict__ vvec,
    const float* __restrict__ c0p, float* __restrict__ out) {
    extern __shared__ char smem[];
    // loop phase : embl bf16 [152 e][2 br][64 b] = 38,912 B
    // epilogue   : mv_t [64][112] at 0, mv_c at +28672 (57,344 B)
    __shared__ float bsum[8];

    const int tid  = threadIdx.x;
    const int lane = tid & 63;
    const int w    = tid >> 6;       // 0..7
    const int grp  = w >> 2;         // e-parity group
    const int w2   = w & 3;          // wave within group
    const int l15  = lane & 15;
    const int l4   = lane >> 4;
    const int m0   = blockIdx.x * BM;

    unsigned short* embl = (unsigned short*)smem;

    // stationary tv A-frags
    short8 afrag[4][4];
#pragma unroll
    for (int mt = 0; mt < 4; ++mt) {
        int bg = m0 + mt * 16 + l15;
#pragma unroll
        for (int ks = 0; ks < 4; ++ks) {
            afrag[mt][ks] = *(const short8*)(tvp + (size_t)bg * KP + ks * 32 + l4 * 8);
        }
    }

    // fragment-order byte offsets within an e-slab
    bool act[2];
    int  loff[2][4];
#pragma unroll
    for (int nt = 0; nt < 2; ++nt) {
        int t = w2 * 2 + nt;         // 0..7 (tile 7 absent)
        act[nt] = (t < 7);
#pragma unroll
        for (int ks = 0; ks < 4; ++ks) {
            loff[nt][ks] = act[nt] ? (((t * 4 + ks) * 64 + lane) * 16) : 0;
        }
    }

    // emb staging (bf16): chunk c covers e in [152c, 152c+152); c=1 incl bias e=300
    auto stage_emb = [&](int c) {
        int b = tid & 63;
        int branch = (tid >> 6) & 1;
        int seg = tid >> 7;              // 0..3
        int ebase = c * 152;
        int nreal = (c == 0) ? 152 : 148;
        int s0 = seg * 40;
        int s1 = s0 + 40; if (s1 > nreal) s1 = nreal;
        const int* idxp = branch ? contexts : targets;
        const float* base = branch ? contextemb : targetemb;
        const float* row = base + (size_t)idxp[m0 + b] * EMB + ebase;
        int off = branch * 64 + b;
        int e = s0;
        for (; e + 4 <= s1; e += 4) {
            float4 v = *(const float4*)(row + e);
            embl[(e + 0) * 128 + off] = f2bf(v.x);
            embl[(e + 1) * 128 + off] = f2bf(v.y);
            embl[(e + 2) * 128 + off] = f2bf(v.z);
            embl[(e + 3) * 128 + off] = f2bf(v.w);
        }
        for (; e < s1; ++e) embl[e * 128 + off] = f2bf(row[e]);
        if (c == 1 && seg == 3) embl[148 * 128 + off] = 0x3F80;  // bias e=300 -> 1.0
    };

    f32x4 acc_t[4][2], acc_c[4][2];
    const f32x4 zf = {0.f, 0.f, 0.f, 0.f};
#pragma unroll
    for (int mt = 0; mt < 4; ++mt) {
#pragma unroll
        for (int nt = 0; nt < 2; ++nt) { acc_t[mt][nt] = zf; acc_c[mt][nt] = zf; }
    }

    auto loadbuf = [&](short8 (&buf)[2][4], int ei) {
        const char* sp = (const char*)ekp + (size_t)ei * EKSTRIDE;
#pragma unroll
        for (int nt = 0; nt < 2; ++nt) {
            if (act[nt]) {
#pragma unroll
                for (int ks = 0; ks < 4; ++ks) {
                    buf[nt][ks] = *(const short8*)(sp + loff[nt][ks]);
                }
            }
        }
    };

    auto compute = [&](int el, short8 (&buf)[2][4]) {
        uint2 dt[4], dc[4];
#pragma unroll
        for (int mt = 0; mt < 4; ++mt) {
            dt[mt] = *(const uint2*)(embl + el * 128 + mt * 16 + l4 * 4);
            dc[mt] = *(const uint2*)(embl + el * 128 + 64 + mt * 16 + l4 * 4);
        }
#pragma unroll
        for (int nt = 0; nt < 2; ++nt) {
            if (act[nt]) {
                f32x4 S[4];
#pragma unroll
                for (int mt = 0; mt < 4; ++mt) S[mt] = zf;
#pragma unroll
                for (int ks = 0; ks < 4; ++ks) {
#pragma unroll
                    for (int mt = 0; mt < 4; ++mt) {
                        S[mt] = __builtin_amdgcn_mfma_f32_16x16x32_bf16(
                            afrag[mt][ks], buf[nt][ks], S[mt], 0, 0, 0);
                    }
                }
#pragma unroll
                for (int mt = 0; mt < 4; ++mt) {
                    float et0 = __uint_as_float(dt[mt].x << 16);
                    float et1 = __uint_as_float(dt[mt].x & 0xffff0000u);
                    float et2 = __uint_as_float(dt[mt].y << 16);
                    float et3 = __uint_as_float(dt[mt].y & 0xffff0000u);
                    float ec0 = __uint_as_float(dc[mt].x << 16);
                    float ec1 = __uint_as_float(dc[mt].x & 0xffff0000u);
                    float ec2 = __uint_as_float(dc[mt].y << 16);
                    float ec3 = __uint_as_float(dc[mt].y & 0xffff0000u);
                    acc_t[mt][nt][0] += et0 * S[mt][0];
                    acc_t[mt][nt][1] += et1 * S[mt][1];
                    acc_t[mt][nt][2] += et2 * S[mt][2];
                    acc_t[mt][nt][3] += et3 * S[mt][3];
                    acc_c[mt][nt][0] += ec0 * S[mt][0];
                    acc_c[mt][nt][1] += ec1 * S[mt][1];
                    acc_c[mt][nt][2] += ec2 * S[mt][2];
                    acc_c[mt][nt][3] += ec3 * S[mt][3];
                }
            }
        }
    };

    stage_emb(0);
    __syncthreads();

    // 2-deep pipelined loop over this group's e sequence: e(i) = grp + 2i
    short8 bufA[2][4], bufB[2][4];
    loadbuf(bufA, grp);
#pragma unroll 1
    for (int i = 0; i < 150; i += 2) {
        if (i == 76) {                 // both groups cross into chunk 1 here
            __syncthreads();
            stage_emb(1);
            __syncthreads();
        }
        int eA = grp + 2 * i;
        int eB = eA + 2;
        loadbuf(bufB, eB);
        compute(eA - (i >= 76 ? 152 : 0), bufA);
        int eC = eA + 4;
        if (eC > 300) eC = 300 - grp;  // grp1: clamp 301 -> 299 (discarded)
        loadbuf(bufA, eC);
        compute(eB - (i + 1 >= 76 ? 152 : 0), bufB);
    }
    if (grp == 0) compute(148, bufA);  // e = 300 (bias row)

    // ---- combine group partials + epilogue ----
    __syncthreads();
    float* mvt = (float*)smem;              // [64][112]
    float* mvc = (float*)(smem + 28672);    // [64][112]
    if (grp == 0) {
#pragma unroll
        for (int mt = 0; mt < 4; ++mt) {
#pragma unroll
            for (int nt = 0; nt < 2; ++nt) {
                if (act[nt]) {
                    int col = (w2 * 2 + nt) * 16 + l15;
#pragma unroll
                    for (int r = 0; r < 4; ++r) {
                        int row = mt * 16 + l4 * 4 + r;
                        mvt[row * 112 + col] = acc_t[mt][nt][r];
                        mvc[row * 112 + col] = acc_c[mt][nt][r];
                    }
                }
            }
        }
    }
    __syncthreads();
    if (grp == 1) {
#pragma unroll
        for (int mt = 0; mt < 4; ++mt) {
#pragma unroll
            for (int nt = 0; nt < 2; ++nt) {
                if (act[nt]) {
                    int col = (w2 * 2 + nt) * 16 + l15;
#pragma unroll
                    for (int r = 0; r < 4; ++r) {
                        int row = mt * 16 + l4 * 4 + r;
                        mvt[row * 112 + col] += acc_t[mt][nt][r];
                        mvc[row * 112 + col] += acc_c[mt][nt][r];
                    }
                }
            }
        }
    }
    __syncthreads();

    int b_loc = tid >> 3;   // 0..63
    int oct   = tid & 7;
    float4 cr[28];
#pragma unroll
    for (int i = 0; i < 28; ++i) cr[i] = *(const float4*)(mvc + b_loc * 112 + i * 4);

    float part = 0.f;
    for (int pp = 0; pp < 14; ++pp) {
        int p = oct * 14 + pp;
        const float4* Grow = (const float4*)(G + p * NP);
        float wq = 0.f;
#pragma unroll 7
        for (int qq = 0; qq < 28; ++qq) {
            float4 g = Grow[qq];
            float4 m = cr[qq];
            wq += g.x * m.x + g.y * m.y + g.z * m.z + g.w * m.w;
        }
        float mtv = mvt[b_loc * 112 + p];
        float mcv = mvc[b_loc * 112 + p];
        part += mtv * wq + vvec[p] * (mtv + mcv);
    }
    part += __shfl_xor(part, 1);
    part += __shfl_xor(part, 2);
    part += __shfl_xor(part, 4);

    float lossv = 0.f;
    if (oct == 0) {
        float logit = part + *c0p;
        float lab = labels[m0 + b_loc];
        lossv = fmaxf(logit, 0.f) - logit * lab + log1pf(expf(-fabsf(logit)));
    }
#pragma unroll
    for (int off = 8; off < 64; off <<= 1) lossv += __shfl_xor(lossv, off);
    if (lane == 0) bsum[w] = lossv;
    __syncthreads();
    if (tid == 0) {
        float s = 0.f;
#pragma unroll
        for (int k = 0; k < 8; ++k) s += bsum[k];
        atomicAdd(out, s * (1.0f / 16384.0f));
    }
}

// ---------------------------------------------------------------------------
extern "C" void kernel_launch(void* const* d_in, const int* in_sizes, int n_in,
                              void* d_out, int out_size, void* d_ws, size_t ws_size,
                              hipStream_t stream) {
    const int*   targets    = (const int*)d_in[0];
    const int*   contexts   = (const int*)d_in[1];
    const float* times      = (const float*)d_in[2];
    const float* labels     = (const float*)d_in[3];
    const float* targetemb  = (const float*)d_in[4];
    const float* contextemb = (const float*)d_in[5];
    const float* h1_k       = (const float*)d_in[6];
    const float* h1_b       = (const float*)d_in[7];
    const float* h2_k       = (const float*)d_in[8];
    const float* h2_b       = (const float*)d_in[9];
    const float* evoke_k    = (const float*)d_in[10];
    const float* evoke_b    = (const float*)d_in[11];
    const float* last_k     = (const float*)d_in[12];
    const float* last_b     = (const float*)d_in[13];
    float* out = (float*)d_out;

    char* ws = (char*)d_ws;
    unsigned short* ekp = (unsigned short*)ws;                 // 301*28672 = 8,630,272
    unsigned short* tvp = (unsigned short*)(ws + 8630272);     // 16384*128*2 = 4,194,304
    float* G   = (float*)(ws + 8630272 + 4194304);             // 128*128*4 = 65,536
    float* vv  = (float*)(ws + 8630272 + 4194304 + 65536);
    float* c0  = (float*)(ws + 8630272 + 4194304 + 65536 + 512);

    k_ekprep<<<dim3(NE), dim3(256), 0, stream>>>(evoke_k, evoke_b, ekp);
    k_tv<<<dim3(BTOT / 16), dim3(256), 0, stream>>>(times, h1_k, h1_b, h2_k, h2_b, tvp);
    k_gprep<<<dim3(16), dim3(256), 77056, stream>>>(last_k, last_b, G, vv, c0, out);
    k_main<<<dim3(BTOT / BM), dim3(512), 57344, stream>>>(
        targets, contexts, labels, targetemb, contextemb, ekp, tvp, G, vv, c0, out);
}